// Round 2
// baseline (95.467 us; speedup 1.0000x reference)
//
#include <hip/hip_runtime.h>

#define S_LEN 20
#define G_CNT 64
#define NPED  128
#define N_TOT 8192
#define M_PTS 200
#define MLP_DIM 1024

// ---------------------------------------------------------------------------
// Kernel 1: counts. Grid = 256 blocks = (group g, quarter q); q owns timesteps
// [5q, 5q+5) for cnt_a AND position indices pi in [640q, 640q+640) for cnt_s
// (pi = t*128 + ped, so the same LDS tile serves both phases).
// ---------------------------------------------------------------------------
__global__ __launch_bounds__(512) void counts_kernel(
    const float2* __restrict__ traj,          // (S, N) as float2
    const int*    __restrict__ seq_scene_ids, // (G,)
    const float2* __restrict__ scenes,        // (8, 200) as float2
    int* __restrict__ cntA, int* __restrict__ cntS)
{
    const int bx  = blockIdx.x;
    const int g   = bx >> 2;
    const int q   = bx & 3;
    const int tid = threadIdx.x;

    __shared__ float2 P[640];        // P[tl*128+ped] = traj[(5q+tl), g*128+ped]
    __shared__ float2 SC[M_PTS];
    __shared__ int    red[512];
    __shared__ int    diffA[130];    // residue difference array (129 used)
    __shared__ int    baseS;

    // ---- stage loads ----
    {
        int tl = tid >> 7, ped = tid & 127;
        P[tid] = traj[(q*5 + tl)*N_TOT + g*NPED + ped];
        if (tid < 128) {
            int idx2 = 512 + tid;           // tl = 4
            P[idx2] = traj[(q*5 + 4)*N_TOT + g*NPED + tid];
        }
        int sid = seq_scene_ids[g];
        if (tid < M_PTS) SC[tid] = scenes[sid*M_PTS + tid];
        if (tid <= 128) diffA[tid] = 0;
        if (tid == 129) baseS = 0;
    }
    __syncthreads();

    // ---- phase A: agent-agent counts (0 < d2 < 0.0625) ----
    {
        const unsigned thrB = __float_as_uint(0.0625f) - 1u;
        const int j = tid & 127, h = tid >> 7;   // j = ped, h = i-chunk
        int c = 0;
        for (int sl = 0; sl < 5; ++sl) {
            float2 xj = P[sl*128 + j];
            #pragma unroll
            for (int ii = 0; ii < 32; ++ii) {
                float2 xi = P[sl*128 + h*32 + ii];   // wave-uniform -> LDS broadcast
                float dx = xj.x - xi.x;
                float dy = xj.y - xi.y;
                // match numpy: round dx*dx and dy*dy separately, then add (no fma)
                float sq = __fadd_rn(__fmul_rn(dx, dx), __fmul_rn(dy, dy));
                // (sq > 0) && (sq < thr): positive-float bit compare
                c += (int)((__float_as_uint(sq) - 1u) < thrB);
            }
        }
        red[tid] = c;
    }

    // ---- phase B: scene counts via run decomposition ----
    // f in [200*pi, 200*pi+200) hits scene indices s0 (and maybe s0+1).
    // A close run [a,b) gives every ped +(L>>7) and peds (a&127 ... +L&127) +1.
    for (int pil = tid; pil < 640; pil += 512) {
        int pi = q*640 + pil;
        float2 pp = P[pil];
        int a0 = pi*200, a1 = a0 + 200;
        int s0 = a0 / 2560;
        int sL = (a1 - 1) / 2560;
        int bnd = (sL > s0) ? sL*2560 : a1;

        {   // run 1: scene s0, f in [a0, bnd)
            float dx = SC[s0].x - pp.x, dy = SC[s0].y - pp.y;
            float d2 = __fadd_rn(__fmul_rn(dx, dx), __fmul_rn(dy, dy));
            if (__float_as_uint(d2) < 0x3f800000u) {   // d2 < 1.0f
                int L = bnd - a0;
                int full = L >> 7, rem = L & 127;
                if (full) atomicAdd(&baseS, full);
                if (rem) {
                    int st = a0 & 127, en = st + rem;
                    atomicAdd(&diffA[st], 1);
                    if (en <= 128) atomicAdd(&diffA[en], -1);
                    else { atomicAdd(&diffA[0], 1); atomicAdd(&diffA[en-128], -1); }
                }
            }
        }
        if (sL > s0) {   // run 2: scene sL, f in [bnd, a1)
            float dx = SC[sL].x - pp.x, dy = SC[sL].y - pp.y;
            float d2 = __fadd_rn(__fmul_rn(dx, dx), __fmul_rn(dy, dy));
            if (__float_as_uint(d2) < 0x3f800000u) {
                int L = a1 - bnd;
                int full = L >> 7, rem = L & 127;
                if (full) atomicAdd(&baseS, full);
                if (rem) {
                    int st = bnd & 127, en = st + rem;
                    atomicAdd(&diffA[st], 1);
                    if (en <= 128) atomicAdd(&diffA[en], -1);
                    else { atomicAdd(&diffA[0], 1); atomicAdd(&diffA[en-128], -1); }
                }
            }
        }
    }
    __syncthreads();

    // ---- finalize: reduce phase-A partials; prefix-sum phase-B diff array ----
    if (tid < 128) {
        int tot = red[tid] + red[tid+128] + red[tid+256] + red[tid+384];
        atomicAdd(&cntA[g*NPED + tid], tot);

        int extra = 0;
        for (int u = 0; u < 128; ++u) {
            int dv = diffA[u];               // LDS broadcast
            if (u <= tid) extra += dv;
        }
        atomicAdd(&cntS[g*NPED + tid], baseS + extra);
    }
}

// ---------------------------------------------------------------------------
// Kernel 2: scalar-input MLPs. Block = 256 threads (4 waves) handles 64
// outputs; lane = output, wave = quarter of the 1024-dim hidden layer.
// Output layout: [0,8192) scores1 (agent), [8192,16384) scores2 (scene).
// ---------------------------------------------------------------------------
__global__ __launch_bounds__(256) void mlp_kernel(
    const int* __restrict__ cntA, const int* __restrict__ cntS,
    const float* __restrict__ w1a, const float* __restrict__ b1a,
    const float* __restrict__ w2a, const float* __restrict__ b2a,
    const float* __restrict__ w1s, const float* __restrict__ b1s,
    const float* __restrict__ w2s, const float* __restrict__ b2s,
    float* __restrict__ out)
{
    const int bx   = blockIdx.x;
    const int tid  = threadIdx.x;
    const int lane = tid & 63;
    const int wv   = tid >> 6;
    const int o    = bx*64 + lane;
    const bool isS = (o >= N_TOT);          // block-uniform (8192 % 64 == 0)

    const float* w1 = isS ? w1s : w1a;
    const float* b1 = isS ? b1s : b1a;
    const float* w2 = isS ? w2s : w2a;
    const float* b2 = isS ? b2s : b2a;

    const int   ci = isS ? cntS[o - N_TOT] : cntA[o];
    const float c  = (float)ci;             // counts < 2^24, exact

    float acc = 0.f;
    const int k0 = wv*256;
    #pragma unroll 8
    for (int k = k0; k < k0 + 256; ++k) {
        float h = fmaxf(__fadd_rn(__fmul_rn(c, w1[k]), b1[k]), 0.f);
        acc = __fadd_rn(acc, __fmul_rn(h, w2[k]));
    }

    __shared__ float part[4][64];
    part[wv][lane] = acc;
    __syncthreads();
    if (tid < 64) {
        out[o] = part[0][tid] + part[1][tid] + part[2][tid] + part[3][tid] + b2[0];
    }
}

extern "C" void kernel_launch(void* const* d_in, const int* in_sizes, int n_in,
                              void* d_out, int out_size, void* d_ws, size_t ws_size,
                              hipStream_t stream)
{
    const float2* traj   = (const float2*)d_in[0];
    // d_in[1] = traj_rel (unused), d_in[2] = seq_start_end (groups are uniform)
    const int*    ssi    = (const int*)d_in[3];
    const float2* scenes = (const float2*)d_in[4];
    const float*  w1a    = (const float*)d_in[5];
    const float*  b1a    = (const float*)d_in[6];
    const float*  w2a    = (const float*)d_in[7];
    const float*  b2a    = (const float*)d_in[8];
    const float*  w1s    = (const float*)d_in[9];
    const float*  b1s    = (const float*)d_in[10];
    const float*  w2s    = (const float*)d_in[11];
    const float*  b2s    = (const float*)d_in[12];

    int* cntA = (int*)d_ws;
    int* cntS = cntA + N_TOT;

    hipMemsetAsync(d_ws, 0, 2*N_TOT*sizeof(int), stream);
    counts_kernel<<<dim3(G_CNT*4), dim3(512), 0, stream>>>(traj, ssi, scenes, cntA, cntS);
    mlp_kernel<<<dim3(256), dim3(256), 0, stream>>>(cntA, cntS,
        w1a, b1a, w2a, b2a, w1s, b1s, w2s, b2s, (float*)d_out);
}

// Round 3
// 94.591 us; speedup vs baseline: 1.0093x; 1.0093x over previous
//
#include <hip/hip_runtime.h>

#define S_LEN 20
#define G_CNT 64
#define NPED  128
#define N_TOT 8192
#define M_PTS 200
#define MLP_DIM 1024

// ---------------------------------------------------------------------------
// Kernel 1: counts. Grid = 256 blocks = (group g, quarter q); q owns timesteps
// [5q, 5q+5) for cnt_a AND position indices pi in [640q, 640q+640) for cnt_s.
// Each block WRITES its partial counts to a private slot partX[q*N_TOT + ...]
// (written exactly once -> no zero-init of d_ws needed, no global atomics).
// ---------------------------------------------------------------------------
__global__ __launch_bounds__(512) void counts_kernel(
    const float2* __restrict__ traj,          // (S, N) as float2
    const int*    __restrict__ seq_scene_ids, // (G,)
    const float2* __restrict__ scenes,        // (8, 200) as float2
    int* __restrict__ partA, int* __restrict__ partS)   // each (4, N_TOT)
{
    const int bx  = blockIdx.x;
    const int g   = bx >> 2;
    const int q   = bx & 3;
    const int tid = threadIdx.x;

    __shared__ float2 P[640];        // P[tl*128+ped] = traj[(5q+tl), g*128+ped]
    __shared__ float2 SC[M_PTS];
    __shared__ int    red[512];
    __shared__ int    diffA[130];    // residue difference array (129 used)
    __shared__ int    baseS;

    // ---- stage loads ----
    {
        int tl = tid >> 7, ped = tid & 127;
        P[tid] = traj[(q*5 + tl)*N_TOT + g*NPED + ped];
        if (tid < 128) {
            P[512 + tid] = traj[(q*5 + 4)*N_TOT + g*NPED + tid];   // tl = 4
        }
        int sid = seq_scene_ids[g];
        if (tid < M_PTS) SC[tid] = scenes[sid*M_PTS + tid];
        if (tid <= 128) diffA[tid] = 0;
        if (tid == 129) baseS = 0;
    }
    __syncthreads();

    // ---- phase A: agent-agent counts (0 < d2 < 0.0625) ----
    {
        const unsigned thrB = __float_as_uint(0.0625f) - 1u;
        const int j = tid & 127, h = tid >> 7;   // j = ped, h = i-chunk
        int c = 0;
        for (int sl = 0; sl < 5; ++sl) {
            float2 xj = P[sl*128 + j];
            #pragma unroll
            for (int ii = 0; ii < 32; ++ii) {
                float2 xi = P[sl*128 + h*32 + ii];   // wave-uniform -> LDS broadcast
                float dx = xj.x - xi.x;
                float dy = xj.y - xi.y;
                // match numpy: round dx*dx and dy*dy separately, then add (no fma)
                float sq = __fadd_rn(__fmul_rn(dx, dx), __fmul_rn(dy, dy));
                // (sq > 0) && (sq < thr): positive-float bit compare
                c += (int)((__float_as_uint(sq) - 1u) < thrB);
            }
        }
        red[tid] = c;
    }

    // ---- phase B: scene counts via run decomposition ----
    // f in [200*pi, 200*pi+200) hits scene indices s0 (and maybe s0+1).
    // A close run [a,b) gives every ped +(L>>7) and a wrapped residue
    // interval starting at (a&127) +1 each.
    for (int pil = tid; pil < 640; pil += 512) {
        int pi = q*640 + pil;
        float2 pp = P[pil];
        int a0 = pi*200, a1 = a0 + 200;
        int s0 = a0 / 2560;
        int sL = (a1 - 1) / 2560;
        int bnd = (sL > s0) ? sL*2560 : a1;

        {   // run 1: scene s0, f in [a0, bnd)
            float dx = SC[s0].x - pp.x, dy = SC[s0].y - pp.y;
            float d2 = __fadd_rn(__fmul_rn(dx, dx), __fmul_rn(dy, dy));
            if (__float_as_uint(d2) < 0x3f800000u) {   // d2 < 1.0f
                int L = bnd - a0;
                int full = L >> 7, rem = L & 127;
                if (full) atomicAdd(&baseS, full);
                if (rem) {
                    int st = a0 & 127, en = st + rem;
                    atomicAdd(&diffA[st], 1);
                    if (en <= 128) atomicAdd(&diffA[en], -1);
                    else { atomicAdd(&diffA[0], 1); atomicAdd(&diffA[en-128], -1); }
                }
            }
        }
        if (sL > s0) {   // run 2: scene sL, f in [bnd, a1)
            float dx = SC[sL].x - pp.x, dy = SC[sL].y - pp.y;
            float d2 = __fadd_rn(__fmul_rn(dx, dx), __fmul_rn(dy, dy));
            if (__float_as_uint(d2) < 0x3f800000u) {
                int L = a1 - bnd;
                int full = L >> 7, rem = L & 127;
                if (full) atomicAdd(&baseS, full);
                if (rem) {
                    int st = bnd & 127, en = st + rem;
                    atomicAdd(&diffA[st], 1);
                    if (en <= 128) atomicAdd(&diffA[en], -1);
                    else { atomicAdd(&diffA[0], 1); atomicAdd(&diffA[en-128], -1); }
                }
            }
        }
    }
    __syncthreads();

    // ---- finalize: reduce phase-A partials; prefix-sum phase-B diff array;
    //      WRITE partials (each slot written exactly once) ----
    if (tid < 128) {
        int tot = red[tid] + red[tid+128] + red[tid+256] + red[tid+384];
        partA[q*N_TOT + g*NPED + tid] = tot;

        int extra = 0;
        for (int u = 0; u < 128; ++u) {
            int dv = diffA[u];               // LDS broadcast
            if (u <= tid) extra += dv;
        }
        partS[q*N_TOT + g*NPED + tid] = baseS + extra;
    }
}

// ---------------------------------------------------------------------------
// Kernel 2: scalar-input MLPs. Block = 256 threads (4 waves) handles 64
// outputs; lane = output, wave = quarter of the 1024-dim hidden layer.
// Output layout: [0,8192) scores1 (agent), [8192,16384) scores2 (scene).
// ---------------------------------------------------------------------------
__global__ __launch_bounds__(256) void mlp_kernel(
    const int* __restrict__ partA, const int* __restrict__ partS,
    const float* __restrict__ w1a, const float* __restrict__ b1a,
    const float* __restrict__ w2a, const float* __restrict__ b2a,
    const float* __restrict__ w1s, const float* __restrict__ b1s,
    const float* __restrict__ w2s, const float* __restrict__ b2s,
    float* __restrict__ out)
{
    const int bx   = blockIdx.x;
    const int tid  = threadIdx.x;
    const int lane = tid & 63;
    const int wv   = tid >> 6;
    const int o    = bx*64 + lane;
    const bool isS = (o >= N_TOT);          // block-uniform (8192 % 64 == 0)

    const float* w1 = isS ? w1s : w1a;
    const float* b1 = isS ? b1s : b1a;
    const float* w2 = isS ? w2s : w2a;
    const float* b2 = isS ? b2s : b2a;
    const int*   pc = isS ? partS : partA;
    const int    oi = isS ? (o - N_TOT) : o;

    const int ci = pc[oi] + pc[N_TOT + oi] + pc[2*N_TOT + oi] + pc[3*N_TOT + oi];
    const float c = (float)ci;              // counts < 2^24, exact

    float acc = 0.f;
    const int k0 = wv*256;
    #pragma unroll 8
    for (int k = k0; k < k0 + 256; ++k) {
        float h = fmaxf(__fadd_rn(__fmul_rn(c, w1[k]), b1[k]), 0.f);
        acc = __fadd_rn(acc, __fmul_rn(h, w2[k]));
    }

    __shared__ float part[4][64];
    part[wv][lane] = acc;
    __syncthreads();
    if (tid < 64) {
        out[o] = part[0][tid] + part[1][tid] + part[2][tid] + part[3][tid] + b2[0];
    }
}

extern "C" void kernel_launch(void* const* d_in, const int* in_sizes, int n_in,
                              void* d_out, int out_size, void* d_ws, size_t ws_size,
                              hipStream_t stream)
{
    const float2* traj   = (const float2*)d_in[0];
    // d_in[1] = traj_rel (unused), d_in[2] = seq_start_end (groups are uniform)
    const int*    ssi    = (const int*)d_in[3];
    const float2* scenes = (const float2*)d_in[4];
    const float*  w1a    = (const float*)d_in[5];
    const float*  b1a    = (const float*)d_in[6];
    const float*  w2a    = (const float*)d_in[7];
    const float*  b2a    = (const float*)d_in[8];
    const float*  w1s    = (const float*)d_in[9];
    const float*  b1s    = (const float*)d_in[10];
    const float*  w2s    = (const float*)d_in[11];
    const float*  b2s    = (const float*)d_in[12];

    int* partA = (int*)d_ws;            // (4, N_TOT)
    int* partS = partA + 4*N_TOT;       // (4, N_TOT)

    counts_kernel<<<dim3(G_CNT*4), dim3(512), 0, stream>>>(traj, ssi, scenes, partA, partS);
    mlp_kernel<<<dim3(256), dim3(256), 0, stream>>>(partA, partS,
        w1a, b1a, w2a, b2a, w1s, b1s, w2s, b2s, (float*)d_out);
}